// Round 12
// baseline (166.550 us; speedup 1.0000x reference)
//
#include <hip/hip_runtime.h>

#define DDIM 128

typedef __bf16 bf16x8 __attribute__((ext_vector_type(8)));
typedef float  floatx4 __attribute__((ext_vector_type(4)));

// ---------------------------------------------------------------------------
// Kernel 1: one N-half of [U|V] = z @ W_combined per block (bf16 MFMA 16x16x32),
// output quantized to BIASED uint8 (code = q+128) with a per-node fp32 scale.
// ROUND-12: CONTIGUOUS register loads + LDS transpose.
// Diagnosis: the old issue_loads was a scattered wave instruction (64 x 16B
// disjoint segments over 16 rows); r9->r10 measured the same scatter costing
// -26% on the DMA path at fixed occupancy. Fix here:
//   - load instruction (rg,cq): lane l reads row base+8rg+(l>>3), 16B unit
//     (l&7) of column-quarter cq -> 8 DENSE 128-B segments per instruction.
//   - fragments recovered via wave-private 8KB LDS tile with XOR swizzle
//     (unit u of row r stored at u^(r&7)); write & read both 8 lanes/bank-
//     group = conflict-free throughput. +16 LDS ops/chunk on an idle pipe.
//   - iteration order: ds_write(rx) -> issue_loads(next)->rx -> ds_read
//     frags -> MFMA -> epilogue  (1-deep prefetch preserved).
// LDS: 32KB W + 32KB A = 64KB -> 2 blocks/CU (r3: 8 waves/CU was neutral vs
// 16 for this kernel). launch_bounds(256,2) -> 256-VGPR cap, no r6 regalloc
// trap. Falsified, do NOT revisit: deeper reg prefetch (spills r4/r6),
// global_load_lds pipeline (r9/r10: 40-54us), more blocks/CU (r11 neutral).
// Epilogue: direct coalesced uint2 stores (permuted col layout: feature
// j*16+p lives at byte p*8+j within each 128-B row).
// ---------------------------------------------------------------------------
__global__ __launch_bounds__(256, 2) void precompute_uv_mfma_q8(
    const float* __restrict__ z, const float* __restrict__ W1,
    const float* __restrict__ b1,
    unsigned char* __restrict__ U8, unsigned char* __restrict__ V8,
    float* __restrict__ u_scale, float* __restrict__ v_scale,
    int N, int nchunks)
{
    __shared__ unsigned short WsF[32 * 64 * 8];      // 32 KiB B-fragments
    __shared__ float As[4][16][128];                 // 32 KiB A-tile (swizzled)

    const int t    = threadIdx.x;
    const int lane = t & 63;
    const int w    = t >> 6;            // wave 0..3
    const int half = blockIdx.x;        // 0 -> U, 1 -> V
    unsigned char* __restrict__ dst8 = half ? V8 : U8;
    float*         __restrict__ dscl = half ? v_scale : u_scale;
    const float*   __restrict__ Wh   = W1 + (size_t)half * DDIM * DDIM;

    const int mrow = lane & 15;    // C/D col within 16-tile (feature sub-index)
    const int quad = lane >> 4;    // C/D row group
    const int gy   = gridDim.y;
    const int rsub = lane >> 3;    // 0..7: row within 8-row group (loads)
    const int usub = lane & 7;     // 0..7: 16B unit within 128B quarter

    // ---- contiguous raw A-tile loads (1-deep prefetch) ----
    // rx[rg*4+cq]: lane l holds z[base+8rg+rsub][cq*32 + usub*4 .. +4]
    float4 rx[8];
    auto issue_loads = [&](int ch) {
        const int base = ch * 64 + w * 16;
        #pragma unroll
        for (int rg = 0; rg < 2; ++rg) {
            int grow = base + 8 * rg + rsub;
            if (grow > N - 1) grow = N - 1;
            const float* zrow = z + (size_t)grow * DDIM;
            #pragma unroll
            for (int cq = 0; cq < 4; ++cq)
                rx[rg * 4 + cq] = *(const float4*)(zrow + cq * 32 + usub * 4);
        }
    };

    // ---- spill rx into the wave-private swizzled LDS tile ----
    // z unit u of row r stored at position (u&~7) | ((u&7)^(r&7)).
    auto write_tile = [&]() {
        #pragma unroll
        for (int rg = 0; rg < 2; ++rg) {
            const int rl = 8 * rg + rsub;
            #pragma unroll
            for (int cq = 0; cq < 4; ++cq) {
                const int pos = cq * 8 + (usub ^ rsub);
                *(float4*)&As[w][rl][pos * 4] = rx[rg * 4 + cq];
            }
        }
    };

    // issue first chunk's loads NOW; latency hides under W-staging below
    if (blockIdx.y < nchunks) issue_loads(blockIdx.y);

    // ---- stage W-half fragments (once per block), packed bf16 via cvt_pk ----
    {
        const int nlow = lane & 15;
        const int kq   = (lane >> 4) & 3;
        #pragma unroll
        for (int i = 0; i < 8; ++i) {
            const int ntks = w + i * 4;              // 0..31
            const int nt = ntks >> 2, ks = ntks & 3;
            const int n  = nt * 16 + nlow;
            const int kb = ks * 32 + kq * 8;
            float f[8];
            #pragma unroll
            for (int j = 0; j < 8; ++j)
                f[j] = Wh[(kb + j) * DDIM + n];
            unsigned pk[4];
            #pragma unroll
            for (int j = 0; j < 4; ++j)
                asm("v_cvt_pk_bf16_f32 %0, %1, %2"
                    : "=v"(pk[j]) : "v"(f[2 * j]), "v"(f[2 * j + 1]));
            *(uint4*)&WsF[(ntks * 64 + lane) * 8] = *(const uint4*)pk;
        }
    }

    // bias per nt (col = nt*16 + mrow); b1 only applies to the U half.
    float bval[8];
    #pragma unroll
    for (int nt = 0; nt < 8; ++nt)
        bval[nt] = (half == 0) ? b1[nt * 16 + mrow] : 0.f;

    __syncthreads();

    for (int chunk = blockIdx.y; chunk < nchunks; chunk += gy) {
        // ---- transpose current chunk through LDS, then prefetch next ----
        write_tile();                       // rx (chunk) -> As[w]
        const int nxt = chunk + gy;
        if (nxt < nchunks) issue_loads(nxt);   // rx free again; loads in flight

        // ---- A fragments from the swizzled tile ----
        // lane needs units ks*8 + quad*2 + h of row mrow; swizzle ^ (mrow&7).
        bf16x8 afrag[4];
        #pragma unroll
        for (int ks = 0; ks < 4; ++ks) {
            const int u0 = ks * 8 + ((quad * 2)     ^ (mrow & 7));
            const int u1 = ks * 8 + ((quad * 2 + 1) ^ (mrow & 7));
            const float4 x0 = *(const float4*)&As[w][mrow][u0 * 4];
            const float4 x1 = *(const float4*)&As[w][mrow][u1 * 4];
            unsigned pk[4];
            asm("v_cvt_pk_bf16_f32 %0, %1, %2" : "=v"(pk[0]) : "v"(x0.x), "v"(x0.y));
            asm("v_cvt_pk_bf16_f32 %0, %1, %2" : "=v"(pk[1]) : "v"(x0.z), "v"(x0.w));
            asm("v_cvt_pk_bf16_f32 %0, %1, %2" : "=v"(pk[2]) : "v"(x1.x), "v"(x1.y));
            asm("v_cvt_pk_bf16_f32 %0, %1, %2" : "=v"(pk[3]) : "v"(x1.z), "v"(x1.w));
            afrag[ks] = __builtin_bit_cast(bf16x8, *(const uint4*)pk);
        }

        floatx4 acc[8];
        #pragma unroll
        for (int nt = 0; nt < 8; ++nt)
            acc[nt] = (floatx4){bval[nt], bval[nt], bval[nt], bval[nt]};

        #pragma unroll
        for (int ks = 0; ks < 4; ++ks) {
            #pragma unroll
            for (int nt = 0; nt < 8; ++nt) {
                const bf16x8 b = __builtin_bit_cast(bf16x8,
                    *(const uint4*)&WsF[((nt * 4 + ks) * 64 + lane) * 8]);
                acc[nt] = __builtin_amdgcn_mfma_f32_16x16x32_bf16(afrag[ks], b, acc[nt], 0, 0, 0);
            }
        }

        // ---- quantize epilogue (direct coalesced stores) ----
        // C-layout: value (nt,r) -> node row quad*4+r (local), col nt*16+mrow.
        #pragma unroll
        for (int r = 0; r < 4; ++r) {
            // triples -> v_max3_f32 with free abs input modifiers
            float mx = fmaxf(fmaxf(fabsf(acc[0][r]), fabsf(acc[1][r])),
                             fabsf(acc[2][r]));
            mx = fmaxf(fmaxf(mx, fabsf(acc[3][r])), fabsf(acc[4][r]));
            mx = fmaxf(fmaxf(mx, fabsf(acc[5][r])), fabsf(acc[6][r]));
            mx = fmaxf(mx, fabsf(acc[7][r]));
            // node row lives across the 16 lanes of this quad-group
            #pragma unroll
            for (int m = 1; m < 16; m <<= 1)
                mx = fmaxf(mx, __shfl_xor(mx, m, 16));
            mx = fmaxf(mx, 1e-20f);
            const float inv = 127.f * __builtin_amdgcn_rcpf(mx);

            // magic = 2^23 + 2^22 + 128 : RNE to integer, low byte = q+128
            unsigned char bytes[8];
            #pragma unroll
            for (int nt = 0; nt < 8; ++nt) {
                const float fq = fmaf(acc[nt][r], inv, 12583040.0f);
                bytes[nt] = (unsigned char)(__builtin_bit_cast(unsigned, fq) & 0xffu);
            }
            const int grow = chunk * 64 + w * 16 + quad * 4 + r;
            if (grow < N) {
                // quad-group covers bytes mrow*8..+7 of the row -> one dense
                // 128 B segment per quad, 4 segments per store instruction.
                *(uint2*)&dst8[(size_t)grow * DDIM + mrow * 8] =
                    *(const uint2*)bytes;
                if (mrow == 0) dscl[grow] = mx * (1.f / 127.f);
            }
        }
    }
}

// ---------------------------------------------------------------------------
// Kernel 2: per-edge gather + relu + dot(W2), 8 lanes/edge, 16-B uint4
// gathers (round-7 proven). Permuted byte layout: row byte b holds feature
// (b&7)*16 + (b>>3). Lane q reads bytes 16q..16q+15 ->
// ww[k] = W2[(k&7)*16 + 2*q + (k>>3)].
// Dequant: h = su*u8f + sv*v8f + c, c = -128*(su+sv) once per edge;
// (x>>8j)&0xff + uitofp matches v_cvt_f32_ubyte{0..3} -> 1 op per byte.
// ---------------------------------------------------------------------------
__global__ __launch_bounds__(256) void edge_kernel_i8(
    const int* __restrict__ ei,
    const unsigned char* __restrict__ U8, const unsigned char* __restrict__ V8,
    const float* __restrict__ u_scale, const float* __restrict__ v_scale,
    const float* __restrict__ W2, const float* __restrict__ b2,
    float* __restrict__ out, int E)
{
    const int t  = threadIdx.x;
    const int q  = t & 7;                              // lane within 8-lane group
    const int g0 = (blockIdx.x * 32 + (t >> 3)) * 4;   // first of 4 edges
    if (g0 >= E) return;

    float ww[16];
    #pragma unroll
    for (int k = 0; k < 16; ++k)
        ww[k] = W2[(k & 7) * 16 + 2 * q + (k >> 3)];

    int rows[4], cols[4];
    if (g0 + 3 < E) {
        const int4 r4 = *(const int4*)(ei + g0);
        const int4 c4 = *(const int4*)(ei + (size_t)E + g0);
        rows[0]=r4.x; rows[1]=r4.y; rows[2]=r4.z; rows[3]=r4.w;
        cols[0]=c4.x; cols[1]=c4.y; cols[2]=c4.z; cols[3]=c4.w;
    } else {
        #pragma unroll
        for (int i = 0; i < 4; ++i) {
            const int gi = (g0 + i < E) ? (g0 + i) : (E - 1);
            rows[i] = ei[gi];
            cols[i] = ei[(size_t)E + gi];
        }
    }

    uint4 uu[4], vv[4];
    #pragma unroll
    for (int i = 0; i < 4; ++i)
        uu[i] = *(const uint4*)(U8 + (size_t)rows[i] * DDIM + q * 16);
    #pragma unroll
    for (int i = 0; i < 4; ++i)
        vv[i] = *(const uint4*)(V8 + (size_t)cols[i] * DDIM + q * 16);

    float su[4], sv[4];
    #pragma unroll
    for (int i = 0; i < 4; ++i) { su[i] = u_scale[rows[i]]; sv[i] = v_scale[cols[i]]; }

    const float bias = b2[0];

    float sres[4];
    #pragma unroll
    for (int i = 0; i < 4; ++i) {
        const unsigned uw0 = uu[i].x, uw1 = uu[i].y, uw2 = uu[i].z, uw3 = uu[i].w;
        const unsigned vw0 = vv[i].x, vw1 = vv[i].y, vw2 = vv[i].z, vw3 = vv[i].w;
        const float c = -128.f * (su[i] + sv[i]);
        float s = 0.f;
        #pragma unroll
        for (int k = 0; k < 16; ++k) {
            const unsigned uwk = (k < 4) ? uw0 : (k < 8) ? uw1 : (k < 12) ? uw2 : uw3;
            const unsigned vwk = (k < 4) ? vw0 : (k < 8) ? vw1 : (k < 12) ? vw2 : vw3;
            const float uf = (float)((uwk >> (8 * (k & 3))) & 0xffu);
            const float vf = (float)((vwk >> (8 * (k & 3))) & 0xffu);
            const float h  = fmaf(su[i], uf, fmaf(sv[i], vf, c));
            s = fmaf(fmaxf(h, 0.f), ww[k], s);
        }
        s += __shfl_down(s, 4, 8);
        s += __shfl_down(s, 2, 8);
        s += __shfl_down(s, 1, 8);
        sres[i] = s + bias;
    }

    if (q == 0) {
        if (g0 + 3 < E) {
            float4 o; o.x = sres[0]; o.y = sres[1]; o.z = sres[2]; o.w = sres[3];
            *(float4*)&out[g0] = o;
        } else {
            #pragma unroll
            for (int i = 0; i < 4; ++i)
                if (g0 + i < E) out[g0 + i] = sres[i];
        }
    }
}

// ---------------------------------------------------------------------------
// Fallback (ws too small): fused per-edge fp32 GEMV (known-correct path).
// ---------------------------------------------------------------------------
__global__ __launch_bounds__(256) void edge_fused_fallback(
    const float* __restrict__ z, const int* __restrict__ ei,
    const float* __restrict__ W1, const float* __restrict__ b1,
    const float* __restrict__ W2, const float* __restrict__ b2,
    float* __restrict__ out, int N, int E)
{
    const int tid  = blockIdx.x * 256 + threadIdx.x;
    const int e    = tid >> 6;
    const int lane = tid & 63;
    if (e >= E) return;

    const int row = ei[e];
    const int col = ei[(size_t)E + e];
    const float* zr = z + (size_t)row * DDIM;
    const float* zc = z + (size_t)col * DDIM;

    float h0 = b1[lane];
    float h1 = b1[lane + 64];
    for (int k = 0; k < DDIM; ++k) {
        const float a = zr[k];
        const float b = zc[k];
        h0 = fmaf(a, W1[k * DDIM + lane],               h0);
        h0 = fmaf(b, W1[(DDIM + k) * DDIM + lane],      h0);
        h1 = fmaf(a, W1[k * DDIM + lane + 64],          h1);
        h1 = fmaf(b, W1[(DDIM + k) * DDIM + lane + 64], h1);
    }
    float s = fmaxf(h0, 0.f) * W2[lane] + fmaxf(h1, 0.f) * W2[lane + 64];
    #pragma unroll
    for (int off = 32; off > 0; off >>= 1)
        s += __shfl_down(s, off, 64);
    if (lane == 0) out[e] = s + b2[0];
}

extern "C" void kernel_launch(void* const* d_in, const int* in_sizes, int n_in,
                              void* d_out, int out_size, void* d_ws, size_t ws_size,
                              hipStream_t stream)
{
    const float* z  = (const float*)d_in[0];
    const int*   ei = (const int*)d_in[1];       // int32 per harness convention
    const float* W1 = (const float*)d_in[2];
    const float* b1 = (const float*)d_in[3];
    const float* W2 = (const float*)d_in[4];
    const float* b2 = (const float*)d_in[5];
    float*       out = (float*)d_out;

    const int N = in_sizes[0] / DDIM;
    const int E = in_sizes[1] / 2;

    const size_t n128 = (size_t)N * DDIM;
    const size_t need = 2 * n128 + 2 * (size_t)N * sizeof(float) + 256;
    if (ws_size >= need) {
        unsigned char* U8 = (unsigned char*)d_ws;
        unsigned char* V8 = U8 + n128;
        float* usc = (float*)(((size_t)(V8 + n128) + 255) & ~(size_t)255);
        float* vsc = usc + N;
        const int nchunks = (N + 63) / 64;
        // 2 x 256 = 512 blocks = 2 resident blocks/CU (64 KiB LDS), single
        // dispatch generation, CPB ~6, contiguous loads + LDS transpose.
        const int gy = nchunks < 256 ? nchunks : 256;
        hipLaunchKernelGGL(precompute_uv_mfma_q8, dim3(2, gy), dim3(256), 0, stream,
                           z, W1, b1, U8, V8, usc, vsc, N, nchunks);
        // edge kernel: 128 edges per 256-thread block (8 lanes/edge, 4/group)
        hipLaunchKernelGGL(edge_kernel_i8, dim3((E + 127) / 128), dim3(256), 0, stream,
                           ei, U8, V8, usc, vsc, W2, b2, out, E);
    } else {
        hipLaunchKernelGGL(edge_fused_fallback, dim3((E + 3) / 4), dim3(256), 0, stream,
                           z, ei, W1, b1, W2, b2, out, N, E);
    }
}

// Round 13
// 138.514 us; speedup vs baseline: 1.2024x; 1.2024x over previous
//
#include <hip/hip_runtime.h>

#define DDIM 128

typedef __bf16 bf16x8 __attribute__((ext_vector_type(8)));
typedef float  floatx4 __attribute__((ext_vector_type(4)));

// ---------------------------------------------------------------------------
// Kernel 1: one N-half of [U|V] = z @ W_combined per block (bf16 MFMA 16x16x32),
// output quantized to BIASED uint8 (code = q+128) with a per-node fp32 scale.
//   half=0: U[n][:] = row n of z@W1[:128] + b1   -> U8 + u_scale
//   half=1: V[n][:] = row n of z@W1[128:]        -> V8 + v_scale
// W-half staged once per block in LDS B-fragment order (32 KiB).
// FINAL (round-13 restore of the round-7 best: 138.65 us total).
// Falsification record for this kernel — all alternatives measured worse or
// neutral; do NOT revisit:
//   r3  merged halves 256thr ......... neutral (occupancy loss cancels gain)
//   r4  512-thr blocks ............... spill (VGPR cap 64) -> 57 MB scratch
//   r5  single-generation grid ....... neutral (tail theory dead)
//   r6  2-deep named-buffer prefetch . spill -> 284 MB scratch, 231 us
//   r9  async global_load_lds ........ 54 us (scattered DMA service rate)
//   r10 contiguous+swizzled DMA ...... 40 us (1 blk/CU, too little TLP)
//   r11 5 blocks/CU .................. neutral (TLP-saturated)
//   r12 contiguous reg loads + LDS ... 60 us (spill + LDS round-trip)
// => ~33 us is the empirical floor of hipcc's scheduling for this
// latency-bound shape (22% HBM, 5% MFMA, 14% VALU at 16 waves/CU).
// Epilogue: direct coalesced uint2 stores (permuted col layout: feature
// j*16+p lives at byte p*8+j within each 128-B row).
// ---------------------------------------------------------------------------
__global__ __launch_bounds__(256, 4) void precompute_uv_mfma_q8(
    const float* __restrict__ z, const float* __restrict__ W1,
    const float* __restrict__ b1,
    unsigned char* __restrict__ U8, unsigned char* __restrict__ V8,
    float* __restrict__ u_scale, float* __restrict__ v_scale,
    int N, int nchunks)
{
    __shared__ unsigned short WsF[32 * 64 * 8];                      // 32 KiB

    const int t    = threadIdx.x;
    const int lane = t & 63;
    const int w    = t >> 6;            // wave 0..3
    const int half = blockIdx.x;        // 0 -> U, 1 -> V
    unsigned char* __restrict__ dst8 = half ? V8 : U8;
    float*         __restrict__ dscl = half ? v_scale : u_scale;
    const float*   __restrict__ Wh   = W1 + (size_t)half * DDIM * DDIM;

    const int mrow = lane & 15;    // C/D col within 16-tile (feature sub-index)
    const int quad = lane >> 4;    // C/D row group
    const int gy   = gridDim.y;

    // ---- raw A-tile register buffer (1-deep prefetch) ----
    float4 rx[8];
    auto issue_loads = [&](int ch) {
        int grow = ch * 64 + w * 16 + mrow;
        if (grow > N - 1) grow = N - 1;
        const float* zrow = z + (size_t)grow * DDIM;
        #pragma unroll
        for (int ks = 0; ks < 4; ++ks) {
            const int k0 = ks * 32 + quad * 8;
            rx[2 * ks]     = *(const float4*)(zrow + k0);
            rx[2 * ks + 1] = *(const float4*)(zrow + k0 + 4);
        }
    };

    // issue first chunk's loads NOW; latency hides under W-staging below
    if (blockIdx.y < nchunks) issue_loads(blockIdx.y);

    // ---- stage W-half fragments (once per block), packed bf16 via cvt_pk ----
    {
        const int nlow = lane & 15;
        const int kq   = (lane >> 4) & 3;
        #pragma unroll
        for (int i = 0; i < 8; ++i) {
            const int ntks = w + i * 4;              // 0..31
            const int nt = ntks >> 2, ks = ntks & 3;
            const int n  = nt * 16 + nlow;
            const int kb = ks * 32 + kq * 8;
            float f[8];
            #pragma unroll
            for (int j = 0; j < 8; ++j)
                f[j] = Wh[(kb + j) * DDIM + n];
            unsigned pk[4];
            #pragma unroll
            for (int j = 0; j < 4; ++j)
                asm("v_cvt_pk_bf16_f32 %0, %1, %2"
                    : "=v"(pk[j]) : "v"(f[2 * j]), "v"(f[2 * j + 1]));
            *(uint4*)&WsF[(ntks * 64 + lane) * 8] = *(const uint4*)pk;
        }
    }

    // bias per nt (col = nt*16 + mrow); b1 only applies to the U half.
    float bval[8];
    #pragma unroll
    for (int nt = 0; nt < 8; ++nt)
        bval[nt] = (half == 0) ? b1[nt * 16 + mrow] : 0.f;

    __syncthreads();

    for (int chunk = blockIdx.y; chunk < nchunks; chunk += gy) {
        // ---- convert raw regs to A fragments ----
        bf16x8 afrag[4];
        #pragma unroll
        for (int ks = 0; ks < 4; ++ks) {
            const float4 x0 = rx[2 * ks];
            const float4 x1 = rx[2 * ks + 1];
            unsigned pk[4];
            asm("v_cvt_pk_bf16_f32 %0, %1, %2" : "=v"(pk[0]) : "v"(x0.x), "v"(x0.y));
            asm("v_cvt_pk_bf16_f32 %0, %1, %2" : "=v"(pk[1]) : "v"(x0.z), "v"(x0.w));
            asm("v_cvt_pk_bf16_f32 %0, %1, %2" : "=v"(pk[2]) : "v"(x1.x), "v"(x1.y));
            asm("v_cvt_pk_bf16_f32 %0, %1, %2" : "=v"(pk[3]) : "v"(x1.z), "v"(x1.w));
            afrag[ks] = __builtin_bit_cast(bf16x8, *(const uint4*)pk);
        }

        // ---- prefetch next chunk's raw A-tile ----
        const int nxt = chunk + gy;
        if (nxt < nchunks) issue_loads(nxt);

        floatx4 acc[8];
        #pragma unroll
        for (int nt = 0; nt < 8; ++nt)
            acc[nt] = (floatx4){bval[nt], bval[nt], bval[nt], bval[nt]};

        #pragma unroll
        for (int ks = 0; ks < 4; ++ks) {
            #pragma unroll
            for (int nt = 0; nt < 8; ++nt) {
                const bf16x8 b = __builtin_bit_cast(bf16x8,
                    *(const uint4*)&WsF[((nt * 4 + ks) * 64 + lane) * 8]);
                acc[nt] = __builtin_amdgcn_mfma_f32_16x16x32_bf16(afrag[ks], b, acc[nt], 0, 0, 0);
            }
        }

        // ---- quantize epilogue (no LDS, direct coalesced stores) ----
        // C-layout: value (nt,r) -> node row quad*4+r (local), col nt*16+mrow.
        #pragma unroll
        for (int r = 0; r < 4; ++r) {
            // triples -> v_max3_f32 with free abs input modifiers
            float mx = fmaxf(fmaxf(fabsf(acc[0][r]), fabsf(acc[1][r])),
                             fabsf(acc[2][r]));
            mx = fmaxf(fmaxf(mx, fabsf(acc[3][r])), fabsf(acc[4][r]));
            mx = fmaxf(fmaxf(mx, fabsf(acc[5][r])), fabsf(acc[6][r]));
            mx = fmaxf(mx, fabsf(acc[7][r]));
            // node row lives across the 16 lanes of this quad-group
            #pragma unroll
            for (int m = 1; m < 16; m <<= 1)
                mx = fmaxf(mx, __shfl_xor(mx, m, 16));
            mx = fmaxf(mx, 1e-20f);
            const float inv = 127.f * __builtin_amdgcn_rcpf(mx);

            // magic = 2^23 + 2^22 + 128 : RNE to integer, low byte = q+128
            unsigned char bytes[8];
            #pragma unroll
            for (int nt = 0; nt < 8; ++nt) {
                const float fq = fmaf(acc[nt][r], inv, 12583040.0f);
                bytes[nt] = (unsigned char)(__builtin_bit_cast(unsigned, fq) & 0xffu);
            }
            const int grow = chunk * 64 + w * 16 + quad * 4 + r;
            if (grow < N) {
                // quad-group covers bytes mrow*8..+7 of the row -> one dense
                // 128 B segment per quad, 4 segments per store instruction.
                *(uint2*)&dst8[(size_t)grow * DDIM + mrow * 8] =
                    *(const uint2*)bytes;
                if (mrow == 0) dscl[grow] = mx * (1.f / 127.f);
            }
        }
    }
}

// ---------------------------------------------------------------------------
// Kernel 2: per-edge gather + relu + dot(W2), 8 lanes/edge, 16-B uint4
// gathers (round-7 proven; ~20 us ~= 10 TB/s effective L2/L3 random-gather
// throughput — near bound, random edges defeat XCD locality). Permuted byte
// layout: row byte b holds feature (b&7)*16 + (b>>3). Lane q reads bytes
// 16q..16q+15 -> ww[k] = W2[(k&7)*16 + 2*q + (k>>3)].
// Dequant: h = su*u8f + sv*v8f + c, c = -128*(su+sv) once per edge;
// (x>>8j)&0xff + uitofp matches v_cvt_f32_ubyte{0..3} -> 1 op per byte.
// ---------------------------------------------------------------------------
__global__ __launch_bounds__(256) void edge_kernel_i8(
    const int* __restrict__ ei,
    const unsigned char* __restrict__ U8, const unsigned char* __restrict__ V8,
    const float* __restrict__ u_scale, const float* __restrict__ v_scale,
    const float* __restrict__ W2, const float* __restrict__ b2,
    float* __restrict__ out, int E)
{
    const int t  = threadIdx.x;
    const int q  = t & 7;                              // lane within 8-lane group
    const int g0 = (blockIdx.x * 32 + (t >> 3)) * 4;   // first of 4 edges
    if (g0 >= E) return;

    float ww[16];
    #pragma unroll
    for (int k = 0; k < 16; ++k)
        ww[k] = W2[(k & 7) * 16 + 2 * q + (k >> 3)];

    int rows[4], cols[4];
    if (g0 + 3 < E) {
        const int4 r4 = *(const int4*)(ei + g0);
        const int4 c4 = *(const int4*)(ei + (size_t)E + g0);
        rows[0]=r4.x; rows[1]=r4.y; rows[2]=r4.z; rows[3]=r4.w;
        cols[0]=c4.x; cols[1]=c4.y; cols[2]=c4.z; cols[3]=c4.w;
    } else {
        #pragma unroll
        for (int i = 0; i < 4; ++i) {
            const int gi = (g0 + i < E) ? (g0 + i) : (E - 1);
            rows[i] = ei[gi];
            cols[i] = ei[(size_t)E + gi];
        }
    }

    uint4 uu[4], vv[4];
    #pragma unroll
    for (int i = 0; i < 4; ++i)
        uu[i] = *(const uint4*)(U8 + (size_t)rows[i] * DDIM + q * 16);
    #pragma unroll
    for (int i = 0; i < 4; ++i)
        vv[i] = *(const uint4*)(V8 + (size_t)cols[i] * DDIM + q * 16);

    float su[4], sv[4];
    #pragma unroll
    for (int i = 0; i < 4; ++i) { su[i] = u_scale[rows[i]]; sv[i] = v_scale[cols[i]]; }

    const float bias = b2[0];

    float sres[4];
    #pragma unroll
    for (int i = 0; i < 4; ++i) {
        const unsigned uw0 = uu[i].x, uw1 = uu[i].y, uw2 = uu[i].z, uw3 = uu[i].w;
        const unsigned vw0 = vv[i].x, vw1 = vv[i].y, vw2 = vv[i].z, vw3 = vv[i].w;
        const float c = -128.f * (su[i] + sv[i]);
        float s = 0.f;
        #pragma unroll
        for (int k = 0; k < 16; ++k) {
            const unsigned uwk = (k < 4) ? uw0 : (k < 8) ? uw1 : (k < 12) ? uw2 : uw3;
            const unsigned vwk = (k < 4) ? vw0 : (k < 8) ? vw1 : (k < 12) ? vw2 : vw3;
            const float uf = (float)((uwk >> (8 * (k & 3))) & 0xffu);
            const float vf = (float)((vwk >> (8 * (k & 3))) & 0xffu);
            const float h  = fmaf(su[i], uf, fmaf(sv[i], vf, c));
            s = fmaf(fmaxf(h, 0.f), ww[k], s);
        }
        s += __shfl_down(s, 4, 8);
        s += __shfl_down(s, 2, 8);
        s += __shfl_down(s, 1, 8);
        sres[i] = s + bias;
    }

    if (q == 0) {
        if (g0 + 3 < E) {
            float4 o; o.x = sres[0]; o.y = sres[1]; o.z = sres[2]; o.w = sres[3];
            *(float4*)&out[g0] = o;
        } else {
            #pragma unroll
            for (int i = 0; i < 4; ++i)
                if (g0 + i < E) out[g0 + i] = sres[i];
        }
    }
}

// ---------------------------------------------------------------------------
// Fallback (ws too small): fused per-edge fp32 GEMV (known-correct path).
// ---------------------------------------------------------------------------
__global__ __launch_bounds__(256) void edge_fused_fallback(
    const float* __restrict__ z, const int* __restrict__ ei,
    const float* __restrict__ W1, const float* __restrict__ b1,
    const float* __restrict__ W2, const float* __restrict__ b2,
    float* __restrict__ out, int N, int E)
{
    const int tid  = blockIdx.x * 256 + threadIdx.x;
    const int e    = tid >> 6;
    const int lane = tid & 63;
    if (e >= E) return;

    const int row = ei[e];
    const int col = ei[(size_t)E + e];
    const float* zr = z + (size_t)row * DDIM;
    const float* zc = z + (size_t)col * DDIM;

    float h0 = b1[lane];
    float h1 = b1[lane + 64];
    for (int k = 0; k < DDIM; ++k) {
        const float a = zr[k];
        const float b = zc[k];
        h0 = fmaf(a, W1[k * DDIM + lane],               h0);
        h0 = fmaf(b, W1[(DDIM + k) * DDIM + lane],      h0);
        h1 = fmaf(a, W1[k * DDIM + lane + 64],          h1);
        h1 = fmaf(b, W1[(DDIM + k) * DDIM + lane + 64], h1);
    }
    float s = fmaxf(h0, 0.f) * W2[lane] + fmaxf(h1, 0.f) * W2[lane + 64];
    #pragma unroll
    for (int off = 32; off > 0; off >>= 1)
        s += __shfl_down(s, off, 64);
    if (lane == 0) out[e] = s + b2[0];
}

extern "C" void kernel_launch(void* const* d_in, const int* in_sizes, int n_in,
                              void* d_out, int out_size, void* d_ws, size_t ws_size,
                              hipStream_t stream)
{
    const float* z  = (const float*)d_in[0];
    const int*   ei = (const int*)d_in[1];       // int32 per harness convention
    const float* W1 = (const float*)d_in[2];
    const float* b1 = (const float*)d_in[3];
    const float* W2 = (const float*)d_in[4];
    const float* b2 = (const float*)d_in[5];
    float*       out = (float*)d_out;

    const int N = in_sizes[0] / DDIM;
    const int E = in_sizes[1] / 2;

    const size_t n128 = (size_t)N * DDIM;
    const size_t need = 2 * n128 + 2 * (size_t)N * sizeof(float) + 256;
    if (ws_size >= need) {
        unsigned char* U8 = (unsigned char*)d_ws;
        unsigned char* V8 = U8 + n128;
        float* usc = (float*)(((size_t)(V8 + n128) + 255) & ~(size_t)255);
        float* vsc = usc + N;
        const int nchunks = (N + 63) / 64;
        // 2 x 512 = 1024 blocks = 4 resident blocks/CU (32 KiB LDS), single
        // dispatch generation, CPB ~3, 1-deep register prefetch (r7 best).
        const int gy = nchunks < 512 ? nchunks : 512;
        hipLaunchKernelGGL(precompute_uv_mfma_q8, dim3(2, gy), dim3(256), 0, stream,
                           z, W1, b1, U8, V8, usc, vsc, N, nchunks);
        // edge kernel: 128 edges per 256-thread block (8 lanes/edge, 4/group)
        hipLaunchKernelGGL(edge_kernel_i8, dim3((E + 127) / 128), dim3(256), 0, stream,
                           ei, U8, V8, usc, vsc, W2, b2, out, E);
    } else {
        hipLaunchKernelGGL(edge_fused_fallback, dim3((E + 3) / 4), dim3(256), 0, stream,
                           z, ei, W1, b1, W2, b2, out, N, E);
    }
}